// Round 13
// baseline (1187.762 us; speedup 1.0000x reference)
//
#include <hip/hip_runtime.h>
#include <hip/hip_fp16.h>

typedef _Float16 f16;
typedef _Float16 f16x8 __attribute__((ext_vector_type(8)));
typedef float f32x4 __attribute__((ext_vector_type(4)));
typedef int int4v __attribute__((ext_vector_type(4)));

#define BM 256
#define BN 256

// ---------------------------------------------------------------------------
// Pre-pass 1: per-row int8 quantization of xs = x/smooth.
// Outputs: Aq[M][K] int8, sx[M] f32, U[M][32] f16 (per-group sums of xs)
// ---------------------------------------------------------------------------
__global__ __launch_bounds__(256) void quantx_kernel(
    const float* __restrict__ x, const float* __restrict__ smooth,
    char* __restrict__ Aq, float* __restrict__ sx, f16* __restrict__ U,
    int M, int K)
{
    const int row = blockIdx.x * 4 + (threadIdx.x >> 6);
    const int lane = threadIdx.x & 63;
    if (row >= M) return;

    f32x4 xsv[16];
    float amax = 0.f;
#pragma unroll
    for (int j = 0; j < 16; ++j) {
        const int k = j * 256 + lane * 4;
        const f32x4 xv = *(const f32x4*)(x + (size_t)row * K + k);
        const f32x4 sv = *(const f32x4*)(smooth + k);
        f32x4 r;
#pragma unroll
        for (int e = 0; e < 4; ++e) {
            r[e] = xv[e] / sv[e];
            amax = fmaxf(amax, fabsf(r[e]));
        }
        xsv[j] = r;
    }
#pragma unroll
    for (int off = 1; off < 64; off <<= 1)
        amax = fmaxf(amax, __shfl_xor(amax, off));
    const float sxr = fmaxf(amax, 1e-20f) / 127.f;
    const float inv = 127.f / fmaxf(amax, 1e-20f);
    if (lane == 0) sx[row] = sxr;

    int* aq32 = (int*)(Aq + (size_t)row * K);
#pragma unroll
    for (int j = 0; j < 16; ++j) {
        unsigned int pk = 0;
        float s4 = 0.f;
#pragma unroll
        for (int e = 0; e < 4; ++e) {
            const float v = xsv[j][e];
            s4 += v;
            int qi = (int)__builtin_rintf(v * inv);
            qi = qi > 127 ? 127 : (qi < -127 ? -127 : qi);
            pk |= ((unsigned int)(qi & 255)) << (8 * e);
        }
        aq32[j * 64 + lane] = (int)pk;
#pragma unroll
        for (int off = 1; off < 32; off <<= 1)
            s4 += __shfl_xor(s4, off);
        if ((lane & 31) == 0)
            U[(size_t)row * 32 + 2 * j + (lane >> 5)] = (f16)s4;
    }
}

// ---------------------------------------------------------------------------
// Pre-pass 2: unpack int32-per-byte nibbles -> Wq[N][K] int8 (q-8, exact).
// ---------------------------------------------------------------------------
__global__ __launch_bounds__(256) void repackw_kernel(
    const int* __restrict__ packed, char* __restrict__ Wq, int total8)
{
    const int i = blockIdx.x * 256 + threadIdx.x;
    if (i >= total8) return;
    const int4v p0 = *(const int4v*)(packed + i * 8);
    const int4v p1 = *(const int4v*)(packed + i * 8 + 4);
    int4v o;
#pragma unroll
    for (int w = 0; w < 4; ++w) {
        const int a = (w < 2) ? p0[2 * w] : p1[2 * (w - 2)];
        const int b = (w < 2) ? p0[2 * w + 1] : p1[2 * (w - 2) + 1];
        const int l0 = ((a & 15) - 8) & 255, h0 = (((a >> 4) & 15) - 8) & 255;
        const int l1 = ((b & 15) - 8) & 255, h1 = (((b >> 4) & 15) - 8) & 255;
        o[w] = l0 | (h0 << 8) | (l1 << 16) | (h1 << 24);
    }
    *(int4v*)(Wq + (size_t)i * 16) = o;
}

// ---------------------------------------------------------------------------
// Pre-pass 3: Vneg[N][32] f16 = -wscale[g][n] * wzero[g][n]
// ---------------------------------------------------------------------------
__global__ __launch_bounds__(256) void vneg_kernel(
    const float* __restrict__ wscale, const float* __restrict__ wzero,
    f16* __restrict__ Vneg, int N)
{
    const int i = blockIdx.x * 256 + threadIdx.x;
    if (i >= N * 32) return;
    const int n = i >> 5;
    const int g = i & 31;
    Vneg[i] = (f16)(-wscale[(size_t)g * N + n] * wzero[(size_t)g * N + n]);
}

// ---------------------------------------------------------------------------
// GEMM (i8 MFMA, NO LDS / NO BARRIERS): each wave owns a 128x64 tile and
// gathers its MFMA fragments directly global->VGPR. Per-lane address
// (row = base + lane&15, 16B at kblk = lane>>4) touches 16 fully-consumed
// 64B lines per load == same line count as a coalesced 1KB load; the 4
// column-waves of a CU re-read identical A lines via L1. Group-major K-128:
// 24 fragment loads, 32 chained MFMA pairs (i32 C through the pair -> ONE
// float fixup per frag per group), no syncs anywhere in the K-loop.
// r9 numerics (absmax 0.375), r7 supertile map, r9 scatter epilogue.
// ---------------------------------------------------------------------------
__global__ __launch_bounds__(512, 2) void gemm_kernel(
    const char* __restrict__ Aq,       // [M][K] int8
    const char* __restrict__ Wq,       // [N][K] int8
    const float* __restrict__ wscale,  // [32][N] f32
    const float* __restrict__ sx,      // [M] f32
    const f16* __restrict__ U,         // [M][32] f16
    const f16* __restrict__ Vneg,      // [N][32] f16
    const float* __restrict__ bias,    // [N]
    float* __restrict__ C,             // [M][N] f32
    int M, int N, int K)
{
    const int t = threadIdx.x;
    const int lane = t & 63;
    const int wid = t >> 6;
    const int wr = wid >> 2;          // 0..1 (M half, 128 rows)
    const int wc = wid & 3;           // 0..3 (N quarter, 64 cols)
    const int fr = lane & 15;
    const int fq = lane >> 4;

    const int nbm = M / BM;           // 32
    const int nbn = N / BN;           // 43
    const int nwg = nbm * nbn;        // 1376
    const int bid = (int)blockIdx.x;

    int bm, bn;
    if (nbm == 32 && nbn == 43) {
        const int x = bid & 7, s = bid >> 3;
        const int r = s >> 5, q = s & 31;
        const int pos = (r < 5) ? (r * 256 + x * 32 + q)
                                : (1280 + x * 12 + (s - 160));
        int st, w;
        if (pos < 1024)      { st = pos >> 8; w = pos & 255; }
        else if (pos < 1200) { st = 4;        w = pos - 1024; }
        else                 { st = 5;        w = pos - 1200; }
        if (st < 4) { bm = (st & 1) * 16 + (w >> 4); bn = (st >> 1) * 16 + (w & 15); }
        else        { bm = (st & 1) * 16 + (w / 11); bn = 32 + (w % 11); }
    } else {
        const int cpx = nwg >> 3;
        const int wg = (bid & 7) * cpx + (bid >> 3);
        bm = wg % nbm; bn = wg / nbm;
    }
    const size_t m0 = (size_t)bm * BM;
    const size_t n0 = (size_t)bn * BN;

    // ---- per-lane fragment base pointers (direct global gather) ----
    const char* pA = Aq + (m0 + wr * 128 + fr) * (size_t)K + fq * 16;
    const char* pW = Wq + (n0 + wc * 64 + fr) * (size_t)K + fq * 16;

    f32x4 accf[8][4];
#pragma unroll
    for (int m = 0; m < 8; ++m)
#pragma unroll
        for (int n = 0; n < 4; ++n)
            accf[m][n] = {0.f, 0.f, 0.f, 0.f};

    const int4v kz = {0, 0, 0, 0};
    const int NG = K >> 7;            // 32 K-128 groups

#pragma unroll 1
    for (int g = 0; g < NG; ++g) {
        const size_t kb0 = (size_t)g * 128;

        // ---- gather the group's 24 fragments (no LDS, no sync) ----
        int4v a0[8], a1[8], b0[4], b1[4];
#pragma unroll
        for (int m = 0; m < 8; ++m) {
            a0[m] = *(const int4v*)(pA + (size_t)m * 16 * K + kb0);
            a1[m] = *(const int4v*)(pA + (size_t)m * 16 * K + kb0 + 64);
        }
#pragma unroll
        for (int n = 0; n < 4; ++n) {
            b0[n] = *(const int4v*)(pW + (size_t)n * 16 * K + kb0);
            b1[n] = *(const int4v*)(pW + (size_t)n * 16 * K + kb0 + 64);
        }
        float sgc[4];
#pragma unroll
        for (int n = 0; n < 4; ++n)
            sgc[n] = wscale[(size_t)g * N + n0 + wc * 64 + n * 16 + fr];

        // ---- 32 chained MFMA pairs + one fixup per frag ----
        __builtin_amdgcn_s_setprio(1);
#pragma unroll
        for (int m = 0; m < 8; ++m)
#pragma unroll
            for (int n = 0; n < 4; ++n) {
                int4v tv = __builtin_amdgcn_mfma_i32_16x16x64_i8(
                    a0[m], b0[n], kz, 0, 0, 0);
                tv = __builtin_amdgcn_mfma_i32_16x16x64_i8(
                    a1[m], b1[n], tv, 0, 0, 0);
#pragma unroll
                for (int e = 0; e < 4; ++e)
                    accf[m][n][e] += sgc[n] * (float)tv[e];
            }
        __builtin_amdgcn_s_setprio(0);
    }

    // ---- epilogue 1: scale by per-row sx ----
#pragma unroll
    for (int m = 0; m < 8; ++m) {
        const f32x4 sxv = *(const f32x4*)(sx + m0 + wr * 128 + m * 16 + fq * 4);
#pragma unroll
        for (int n = 0; n < 4; ++n)
#pragma unroll
            for (int e = 0; e < 4; ++e)
                accf[m][n][e] *= sxv[e];
    }

    // ---- epilogue 2: rank-32 zero-point correction via f16 MFMA ----
    {
        f16x8 uf[8], vf[4];
#pragma unroll
        for (int m = 0; m < 8; ++m)
            uf[m] = *(const f16x8*)(U + (m0 + wr * 128 + m * 16 + fr) * 32 + fq * 8);
#pragma unroll
        for (int n = 0; n < 4; ++n)
            vf[n] = *(const f16x8*)(Vneg + (n0 + wc * 64 + n * 16 + fr) * 32 + fq * 8);
#pragma unroll
        for (int m = 0; m < 8; ++m)
#pragma unroll
            for (int n = 0; n < 4; ++n)
                accf[m][n] = __builtin_amdgcn_mfma_f32_16x16x32_f16(
                    uf[m], vf[n], accf[m][n], 0, 0, 0);
    }

    // ---- epilogue 3: + bias, f32 scatter stores (static indices) ----
#pragma unroll
    for (int n = 0; n < 4; ++n) {
        const size_t gcol = n0 + wc * 64 + n * 16 + fr;
        const float bv = bias[gcol];
#pragma unroll
        for (int am = 0; am < 8; ++am) {
            const size_t grow = m0 + wr * 128 + am * 16 + fq * 4;
#pragma unroll
            for (int r = 0; r < 4; ++r)
                C[(grow + r) * N + gcol] = accf[am][n][r] + bv;
        }
    }
}

extern "C" void kernel_launch(void* const* d_in, const int* in_sizes, int n_in,
                              void* d_out, int out_size, void* d_ws, size_t ws_size,
                              hipStream_t stream) {
    const float* x      = (const float*)d_in[0];
    const int* packed   = (const int*)d_in[1];
    const float* wscale = (const float*)d_in[2];
    const float* wzero  = (const float*)d_in[3];
    const float* smooth = (const float*)d_in[4];
    const float* bias   = (const float*)d_in[5];
    float* out = (float*)d_out;

    const int K = in_sizes[4];             // 4096
    const int N = in_sizes[5];             // 11008
    const int M = in_sizes[0] / K;         // 8192
    const size_t MK = (size_t)M * K;
    const size_t NK = (size_t)N * K;

    char* Aq  = (char*)d_ws;
    char* Wq  = Aq + MK;
    f16* U    = (f16*)(Wq + NK);
    f16* Vneg = U + (size_t)M * 32;
    float* sxp = (float*)(Vneg + (size_t)N * 32);

    quantx_kernel<<<(M + 3) / 4, 256, 0, stream>>>(x, smooth, Aq, sxp, U, M, K);
    const int total8 = (int)(NK / 16);
    repackw_kernel<<<(total8 + 255) / 256, 256, 0, stream>>>(packed, Wq, total8);
    vneg_kernel<<<(N * 32 + 255) / 256, 256, 0, stream>>>(wscale, wzero, Vneg, N);

    const int grid_gemm = (M / BM) * (N / BN);
    gemm_kernel<<<grid_gemm, 512, 0, stream>>>(
        Aq, Wq, wscale, sxp, U, Vneg, bias, out, M, N, K);
}

// Round 14
// 674.820 us; speedup vs baseline: 1.7601x; 1.7601x over previous
//
#include <hip/hip_runtime.h>
#include <hip/hip_fp16.h>

typedef _Float16 f16;
typedef _Float16 f16x8 __attribute__((ext_vector_type(8)));
typedef float f32x4 __attribute__((ext_vector_type(4)));
typedef int int4v __attribute__((ext_vector_type(4)));

#define BM 256
#define BN 256
#define NBUF 4
#define BUFSZ 32768              // A 16KB + B 16KB (int8, K-tile = 64)

typedef const __attribute__((address_space(1))) unsigned int* gas_ptr;
typedef __attribute__((address_space(3))) unsigned int* las_ptr;

__device__ __forceinline__ void gload_lds16(const void* g, void* l) {
    __builtin_amdgcn_global_load_lds((gas_ptr)g, (las_ptr)l, 16, 0, 0);
}

// ---------------------------------------------------------------------------
// Pre-pass 1: per-row int8 quantization of xs = x/smooth.
// Outputs: Aq[M][K] int8, sx[M] f32, U[M][32] f16 (per-group sums of xs)
// ---------------------------------------------------------------------------
__global__ __launch_bounds__(256) void quantx_kernel(
    const float* __restrict__ x, const float* __restrict__ smooth,
    char* __restrict__ Aq, float* __restrict__ sx, f16* __restrict__ U,
    int M, int K)
{
    const int row = blockIdx.x * 4 + (threadIdx.x >> 6);
    const int lane = threadIdx.x & 63;
    if (row >= M) return;

    f32x4 xsv[16];
    float amax = 0.f;
#pragma unroll
    for (int j = 0; j < 16; ++j) {
        const int k = j * 256 + lane * 4;
        const f32x4 xv = *(const f32x4*)(x + (size_t)row * K + k);
        const f32x4 sv = *(const f32x4*)(smooth + k);
        f32x4 r;
#pragma unroll
        for (int e = 0; e < 4; ++e) {
            r[e] = xv[e] / sv[e];
            amax = fmaxf(amax, fabsf(r[e]));
        }
        xsv[j] = r;
    }
#pragma unroll
    for (int off = 1; off < 64; off <<= 1)
        amax = fmaxf(amax, __shfl_xor(amax, off));
    const float sxr = fmaxf(amax, 1e-20f) / 127.f;
    const float inv = 127.f / fmaxf(amax, 1e-20f);
    if (lane == 0) sx[row] = sxr;

    int* aq32 = (int*)(Aq + (size_t)row * K);
#pragma unroll
    for (int j = 0; j < 16; ++j) {
        unsigned int pk = 0;
        float s4 = 0.f;
#pragma unroll
        for (int e = 0; e < 4; ++e) {
            const float v = xsv[j][e];
            s4 += v;
            int qi = (int)__builtin_rintf(v * inv);
            qi = qi > 127 ? 127 : (qi < -127 ? -127 : qi);
            pk |= ((unsigned int)(qi & 255)) << (8 * e);
        }
        aq32[j * 64 + lane] = (int)pk;
#pragma unroll
        for (int off = 1; off < 32; off <<= 1)
            s4 += __shfl_xor(s4, off);
        if ((lane & 31) == 0)
            U[(size_t)row * 32 + 2 * j + (lane >> 5)] = (f16)s4;
    }
}

// ---------------------------------------------------------------------------
// Pre-pass 2: unpack int32-per-byte nibbles -> Wq[N][K] int8 (q-8, exact).
// ---------------------------------------------------------------------------
__global__ __launch_bounds__(256) void repackw_kernel(
    const int* __restrict__ packed, char* __restrict__ Wq, int total8)
{
    const int i = blockIdx.x * 256 + threadIdx.x;
    if (i >= total8) return;
    const int4v p0 = *(const int4v*)(packed + i * 8);
    const int4v p1 = *(const int4v*)(packed + i * 8 + 4);
    int4v o;
#pragma unroll
    for (int w = 0; w < 4; ++w) {
        const int a = (w < 2) ? p0[2 * w] : p1[2 * (w - 2)];
        const int b = (w < 2) ? p0[2 * w + 1] : p1[2 * (w - 2) + 1];
        const int l0 = ((a & 15) - 8) & 255, h0 = (((a >> 4) & 15) - 8) & 255;
        const int l1 = ((b & 15) - 8) & 255, h1 = (((b >> 4) & 15) - 8) & 255;
        o[w] = l0 | (h0 << 8) | (l1 << 16) | (h1 << 24);
    }
    *(int4v*)(Wq + (size_t)i * 16) = o;
}

// ---------------------------------------------------------------------------
// Pre-pass 3: Vneg[N][32] f16 = -wscale[g][n] * wzero[g][n]
// ---------------------------------------------------------------------------
__global__ __launch_bounds__(256) void vneg_kernel(
    const float* __restrict__ wscale, const float* __restrict__ wzero,
    f16* __restrict__ Vneg, int N)
{
    const int i = blockIdx.x * 256 + threadIdx.x;
    if (i >= N * 32) return;
    const int n = i >> 5;
    const int g = i & 31;
    Vneg[i] = (f16)(-wscale[(size_t)g * N + n] * wzero[(size_t)g * N + n]);
}

// ---------------------------------------------------------------------------
// GEMM (i8 MFMA, group-major, STREAMED A): ONE barrier + ONE vmcnt(0) per
// K-128 group (r9 structure). Delta vs r9: B fragments resident (8 frags,
// 32 VGPR); A fragment pairs streamed per m-iteration (2 ds_reads -> 4
// chained MFMA pairs + fixups). Frees ~56 VGPRs (r9 ran at the 256-reg cap,
// forcing serialized fixup chains) and interleaves LDS reads through the
// whole group so ds_read overlaps MFMA.
// r9-proven staging geometry / XOR swizzle (0 conflicts) / supertile map /
// numerics (absmax 0.375) / epilogues.
// ---------------------------------------------------------------------------
__global__ __launch_bounds__(512, 2) void gemm_kernel(
    const char* __restrict__ Aq,       // [M][K] int8
    const char* __restrict__ Wq,       // [N][K] int8
    const float* __restrict__ wscale,  // [32][N] f32
    const float* __restrict__ sx,      // [M] f32
    const f16* __restrict__ U,         // [M][32] f16
    const f16* __restrict__ Vneg,      // [N][32] f16
    const float* __restrict__ bias,    // [N]
    float* __restrict__ C,             // [M][N] f32
    int M, int N, int K)
{
    __shared__ char lds[NBUF * BUFSZ];   // 128 KiB

    const int t = threadIdx.x;
    const int lane = t & 63;
    const int wid = t >> 6;
    const int wr = wid >> 2;          // 0..1
    const int wc = wid & 3;           // 0..3
    const int fr = lane & 15;
    const int fq = lane >> 4;

    const int nbm = M / BM;           // 32
    const int nbn = N / BN;           // 43
    const int nwg = nbm * nbn;        // 1376
    const int bid = (int)blockIdx.x;

    int bm, bn;
    if (nbm == 32 && nbn == 43) {
        const int x = bid & 7, s = bid >> 3;
        const int r = s >> 5, q = s & 31;
        const int pos = (r < 5) ? (r * 256 + x * 32 + q)
                                : (1280 + x * 12 + (s - 160));
        int st, w;
        if (pos < 1024)      { st = pos >> 8; w = pos & 255; }
        else if (pos < 1200) { st = 4;        w = pos - 1024; }
        else                 { st = 5;        w = pos - 1200; }
        if (st < 4) { bm = (st & 1) * 16 + (w >> 4); bn = (st >> 1) * 16 + (w & 15); }
        else        { bm = (st & 1) * 16 + (w / 11); bn = 32 + (w % 11); }
    } else {
        const int cpx = nwg >> 3;
        const int wg = (bid & 7) * cpx + (bid >> 3);
        bm = wg % nbm; bn = wg / nbm;
    }
    const size_t m0 = (size_t)bm * BM;
    const size_t n0 = (size_t)bn * BN;

    // ---- staging geometry (512 threads, 8KB per gload; r9-verified) ----
    const int scv = (t & 7) ^ ((t >> 3) & 7);
    const int rbase = 2 * (t >> 3) + (scv >> 2);   // 0..127
    const int kb = (scv & 3) * 16;                 // byte offset in 64B row
    const char* gAq = Aq + (m0 + rbase) * (size_t)K + kb;
    const char* gWq = Wq + (n0 + rbase) * (size_t)K + kb;

#define STAGE_A(sb, Tst) do { char* _d = lds + (sb) + t * 16; \
    gload_lds16(gAq + (size_t)(Tst) * 64, _d); \
    gload_lds16(gAq + (size_t)128 * K + (size_t)(Tst) * 64, _d + 8192); } while (0)
#define STAGE_B(sb, Tst) do { char* _d = lds + (sb) + 16384 + t * 16; \
    gload_lds16(gWq + (size_t)(Tst) * 64, _d); \
    gload_lds16(gWq + (size_t)128 * K + (size_t)(Tst) * 64, _d + 8192); } while (0)

    // ---- ds_read lane constants (r3/r7/r9-proven swizzle) ----
    const int aswz = ((((fr & 1) << 2) | fq) ^ ((fr >> 1) & 7)) << 4;
    const int aBase = wr * 8192 + ((fr >> 1) << 7) + aswz;
    const int bBase = 16384 + wc * 4096 + ((fr >> 1) << 7) + aswz;

#define LDA(db, m) (*(const int4v*)(lds + (db) + aBase + (m) * 1024))
#define LDB(db, n) (*(const int4v*)(lds + (db) + bBase + (n) * 1024))

    f32x4 accf[8][4];
#pragma unroll
    for (int m = 0; m < 8; ++m)
#pragma unroll
        for (int n = 0; n < 4; ++n)
            accf[m][n] = {0.f, 0.f, 0.f, 0.f};

    const int4v kz = {0, 0, 0, 0};
    const int NG = K >> 7;            // 32 groups of K=128 (2 K-64 tiles)

    // ---- prologue: stage group 0 (tiles 0,1); preload its scales ----
    STAGE_A(0, 0); STAGE_B(0, 0);
    STAGE_A(BUFSZ, 1); STAGE_B(BUFSZ, 1);
    float sgc[4];
#pragma unroll
    for (int n = 0; n < 4; ++n)
        sgc[n] = wscale[n0 + wc * 64 + n * 16 + fr];
    asm volatile("s_waitcnt vmcnt(0)" ::: "memory");
    __builtin_amdgcn_s_barrier();

#pragma unroll 1
    for (int g = 0; g < NG; ++g) {
        const int db0 = ((2 * g)     & 3) * BUFSZ;
        const int db1 = ((2 * g + 1) & 3) * BUFSZ;
        const bool hn = (g + 1) < NG;

        // ---- issue next group's stages FIRST (age a full group) ----
        if (hn) {
            const int sb0 = ((2 * g + 2) & 3) * BUFSZ;
            const int sb1 = ((2 * g + 3) & 3) * BUFSZ;
            STAGE_A(sb0, 2 * g + 2); STAGE_B(sb0, 2 * g + 2);
            STAGE_A(sb1, 2 * g + 3); STAGE_B(sb1, 2 * g + 3);
        }
        // ---- prefetch next group's scales ----
        float sgn[4] = {sgc[0], sgc[1], sgc[2], sgc[3]};
        if (hn) {
#pragma unroll
            for (int n = 0; n < 4; ++n)
                sgn[n] = wscale[(size_t)(g + 1) * N + n0 + wc * 64 + n * 16 + fr];
        }

        // ---- resident B fragments (8 reads, 32 VGPR) ----
        int4v b0[4], b1[4];
#pragma unroll
        for (int n = 0; n < 4; ++n) { b0[n] = LDB(db0, n); b1[n] = LDB(db1, n); }

        // ---- stream A pairs: 2 ds_reads -> 4 chained pairs + fixups ----
        __builtin_amdgcn_s_setprio(1);
#pragma unroll
        for (int m = 0; m < 8; ++m) {
            const int4v a0 = LDA(db0, m);
            const int4v a1 = LDA(db1, m);
#pragma unroll
            for (int n = 0; n < 4; ++n) {
                int4v tv = __builtin_amdgcn_mfma_i32_16x16x64_i8(
                    a0, b0[n], kz, 0, 0, 0);
                tv = __builtin_amdgcn_mfma_i32_16x16x64_i8(
                    a1, b1[n], tv, 0, 0, 0);
#pragma unroll
                for (int e = 0; e < 4; ++e)
                    accf[m][n][e] += sgc[n] * (float)tv[e];
            }
        }
        __builtin_amdgcn_s_setprio(0);

#pragma unroll
        for (int n = 0; n < 4; ++n) sgc[n] = sgn[n];

        // ---- single group-boundary sync ----
        asm volatile("s_waitcnt vmcnt(0)" ::: "memory");
        __builtin_amdgcn_s_barrier();
    }

    // ---- epilogue 1: scale by per-row sx ----
#pragma unroll
    for (int m = 0; m < 8; ++m) {
        const f32x4 sxv = *(const f32x4*)(sx + m0 + wr * 128 + m * 16 + fq * 4);
#pragma unroll
        for (int n = 0; n < 4; ++n)
#pragma unroll
            for (int e = 0; e < 4; ++e)
                accf[m][n][e] *= sxv[e];
    }

    // ---- epilogue 2: rank-32 zero-point correction via f16 MFMA ----
    {
        f16x8 uf[8], vf[4];
#pragma unroll
        for (int m = 0; m < 8; ++m)
            uf[m] = *(const f16x8*)(U + (m0 + wr * 128 + m * 16 + fr) * 32 + fq * 8);
#pragma unroll
        for (int n = 0; n < 4; ++n)
            vf[n] = *(const f16x8*)(Vneg + (n0 + wc * 64 + n * 16 + fr) * 32 + fq * 8);
#pragma unroll
        for (int m = 0; m < 8; ++m)
#pragma unroll
            for (int n = 0; n < 4; ++n)
                accf[m][n] = __builtin_amdgcn_mfma_f32_16x16x32_f16(
                    uf[m], vf[n], accf[m][n], 0, 0, 0);
    }

    // ---- epilogue 3: + bias, f32 scatter stores (static indices) ----
#pragma unroll
    for (int n = 0; n < 4; ++n) {
        const size_t gcol = n0 + wc * 64 + n * 16 + fr;
        const float bv = bias[gcol];
#pragma unroll
        for (int am = 0; am < 8; ++am) {
            const size_t grow = m0 + wr * 128 + am * 16 + fq * 4;
#pragma unroll
            for (int r = 0; r < 4; ++r)
                C[(grow + r) * N + gcol] = accf[am][n][r] + bv;
        }
    }
}

extern "C" void kernel_launch(void* const* d_in, const int* in_sizes, int n_in,
                              void* d_out, int out_size, void* d_ws, size_t ws_size,
                              hipStream_t stream) {
    const float* x      = (const float*)d_in[0];
    const int* packed   = (const int*)d_in[1];
    const float* wscale = (const float*)d_in[2];
    const float* wzero  = (const float*)d_in[3];
    const float* smooth = (const float*)d_in[4];
    const float* bias   = (const float*)d_in[5];
    float* out = (float*)d_out;

    const int K = in_sizes[4];             // 4096
    const int N = in_sizes[5];             // 11008
    const int M = in_sizes[0] / K;         // 8192
    const size_t MK = (size_t)M * K;
    const size_t NK = (size_t)N * K;

    char* Aq  = (char*)d_ws;
    char* Wq  = Aq + MK;
    f16* U    = (f16*)(Wq + NK);
    f16* Vneg = U + (size_t)M * 32;
    float* sxp = (float*)(Vneg + (size_t)N * 32);

    quantx_kernel<<<(M + 3) / 4, 256, 0, stream>>>(x, smooth, Aq, sxp, U, M, K);
    const int total8 = (int)(NK / 16);
    repackw_kernel<<<(total8 + 255) / 256, 256, 0, stream>>>(packed, Wq, total8);
    vneg_kernel<<<(N * 32 + 255) / 256, 256, 0, stream>>>(wscale, wzero, Vneg, N);

    const int grid_gemm = (M / BM) * (N / BN);
    gemm_kernel<<<grid_gemm, 512, 0, stream>>>(
        Aq, Wq, wscale, sxp, U, Vneg, bias, out, M, N, K);
}

// Round 15
// 638.793 us; speedup vs baseline: 1.8594x; 1.0564x over previous
//
#include <hip/hip_runtime.h>
#include <hip/hip_fp16.h>

typedef _Float16 f16;
typedef _Float16 f16x8 __attribute__((ext_vector_type(8)));
typedef float f32x4 __attribute__((ext_vector_type(4)));
typedef int int4v __attribute__((ext_vector_type(4)));

#define BM 128
#define BN 128
// BK = 128 int8 (one quant group per tile); NBUF=2; buffer = A 16KB + B 16KB.

typedef const __attribute__((address_space(1))) unsigned int* gas_ptr;
typedef __attribute__((address_space(3))) unsigned int* las_ptr;

__device__ __forceinline__ void gload_lds16(const void* g, void* l) {
    __builtin_amdgcn_global_load_lds((gas_ptr)g, (las_ptr)l, 16, 0, 0);
}

// ---------------------------------------------------------------------------
// Pre-pass 1: per-row int8 quantization of xs = x/smooth.
// Outputs: Aq[M][K] int8, sx[M] f32, U[M][32] f16 (per-group sums of xs)
// ---------------------------------------------------------------------------
__global__ __launch_bounds__(256) void quantx_kernel(
    const float* __restrict__ x, const float* __restrict__ smooth,
    char* __restrict__ Aq, float* __restrict__ sx, f16* __restrict__ U,
    int M, int K)
{
    const int row = blockIdx.x * 4 + (threadIdx.x >> 6);
    const int lane = threadIdx.x & 63;
    if (row >= M) return;

    f32x4 xsv[16];
    float amax = 0.f;
#pragma unroll
    for (int j = 0; j < 16; ++j) {
        const int k = j * 256 + lane * 4;
        const f32x4 xv = *(const f32x4*)(x + (size_t)row * K + k);
        const f32x4 sv = *(const f32x4*)(smooth + k);
        f32x4 r;
#pragma unroll
        for (int e = 0; e < 4; ++e) {
            r[e] = xv[e] / sv[e];
            amax = fmaxf(amax, fabsf(r[e]));
        }
        xsv[j] = r;
    }
#pragma unroll
    for (int off = 1; off < 64; off <<= 1)
        amax = fmaxf(amax, __shfl_xor(amax, off));
    const float sxr = fmaxf(amax, 1e-20f) / 127.f;
    const float inv = 127.f / fmaxf(amax, 1e-20f);
    if (lane == 0) sx[row] = sxr;

    int* aq32 = (int*)(Aq + (size_t)row * K);
#pragma unroll
    for (int j = 0; j < 16; ++j) {
        unsigned int pk = 0;
        float s4 = 0.f;
#pragma unroll
        for (int e = 0; e < 4; ++e) {
            const float v = xsv[j][e];
            s4 += v;
            int qi = (int)__builtin_rintf(v * inv);
            qi = qi > 127 ? 127 : (qi < -127 ? -127 : qi);
            pk |= ((unsigned int)(qi & 255)) << (8 * e);
        }
        aq32[j * 64 + lane] = (int)pk;
#pragma unroll
        for (int off = 1; off < 32; off <<= 1)
            s4 += __shfl_xor(s4, off);
        if ((lane & 31) == 0)
            U[(size_t)row * 32 + 2 * j + (lane >> 5)] = (f16)s4;
    }
}

// ---------------------------------------------------------------------------
// Pre-pass 2: unpack int32-per-byte nibbles -> Wq[N][K] int8 (q-8, exact).
// ---------------------------------------------------------------------------
__global__ __launch_bounds__(256) void repackw_kernel(
    const int* __restrict__ packed, char* __restrict__ Wq, int total8)
{
    const int i = blockIdx.x * 256 + threadIdx.x;
    if (i >= total8) return;
    const int4v p0 = *(const int4v*)(packed + i * 8);
    const int4v p1 = *(const int4v*)(packed + i * 8 + 4);
    int4v o;
#pragma unroll
    for (int w = 0; w < 4; ++w) {
        const int a = (w < 2) ? p0[2 * w] : p1[2 * (w - 2)];
        const int b = (w < 2) ? p0[2 * w + 1] : p1[2 * (w - 2) + 1];
        const int l0 = ((a & 15) - 8) & 255, h0 = (((a >> 4) & 15) - 8) & 255;
        const int l1 = ((b & 15) - 8) & 255, h1 = (((b >> 4) & 15) - 8) & 255;
        o[w] = l0 | (h0 << 8) | (l1 << 16) | (h1 << 24);
    }
    *(int4v*)(Wq + (size_t)i * 16) = o;
}

// ---------------------------------------------------------------------------
// Pre-pass 3: Vneg[N][32] f16 = -wscale[g][n] * wzero[g][n]
// ---------------------------------------------------------------------------
__global__ __launch_bounds__(256) void vneg_kernel(
    const float* __restrict__ wscale, const float* __restrict__ wzero,
    f16* __restrict__ Vneg, int N)
{
    const int i = blockIdx.x * 256 + threadIdx.x;
    if (i >= N * 32) return;
    const int n = i >> 5;
    const int g = i & 31;
    Vneg[i] = (f16)(-wscale[(size_t)g * N + n] * wzero[(size_t)g * N + n]);
}

// ---------------------------------------------------------------------------
// GEMM (i8 MFMA, 2 INDEPENDENT BLOCKS/CU): 128x128 tile, BK=128 (= one quant
// group per step), 4 waves (2x2, wave 64x64, acc=64), NBUF=2 -> 64KB LDS ->
// 2 co-resident blocks cover each other's group-boundary drains (m114).
// Per step: stage next tile into other buf at top; resident B frags (8),
// streamed A pairs -> chained MFMA pairs (ONE fixup per frag per K-128);
// one vmcnt(0)+barrier per step. Register demand ~135 << 256 cap: no spill.
// LDS: row = one 128B line; chunkpos c holds global chunk c^(row&7)
// (same verified involution; gload dests linear, source pre-swizzled).
// ---------------------------------------------------------------------------
__global__ __launch_bounds__(256, 2) void gemm_kernel(
    const char* __restrict__ Aq,       // [M][K] int8
    const char* __restrict__ Wq,       // [N][K] int8
    const float* __restrict__ wscale,  // [32][N] f32
    const float* __restrict__ sx,      // [M] f32
    const f16* __restrict__ U,         // [M][32] f16
    const f16* __restrict__ Vneg,      // [N][32] f16
    const float* __restrict__ bias,    // [N]
    float* __restrict__ C,             // [M][N] f32
    int M, int N, int K)
{
    __shared__ char lds[2 * 32768];      // 64 KiB

    const int t = threadIdx.x;
    const int lane = t & 63;
    const int wid = t >> 6;
    const int wr = wid >> 1;          // 0..1 (M half)
    const int wc = wid & 1;           // 0..1 (N half)
    const int fr = lane & 15;
    const int fq = lane >> 4;

    const int nbm = M / BM;           // 64
    const int nbn = N / BN;           // 86
    const int nwg = nbm * nbn;        // 5504, %8 == 0
    const int bid = (int)blockIdx.x;
    const int cpx = nwg >> 3;
    const int wg = ((nwg & 7) == 0) ? ((bid & 7) * cpx + (bid >> 3)) : bid;
    const int bm = wg % nbm;          // bm-major: consecutive wg share B panel
    const int bn = wg / nbm;
    const size_t m0 = (size_t)bm * BM;
    const size_t n0 = (size_t)bn * BN;

    // ---- staging geometry: thread t covers 4 chunk-quarters of row rq ----
    // dest (linear): quarter j at j*4096 + t*16 -> row j*32 + w*8 + (l>>3),
    // chunkpos l&7; content chunk = (l&7) ^ (row&7), row&7 = (l>>3)&7.
    const int l = lane, w = wid;
    const int sc = (l & 7) ^ ((l >> 3) & 7);
    const int rq = w * 8 + (l >> 3);               // 0..31
    const char* gAs = Aq + (m0 + rq) * (size_t)K + sc * 16;
    const char* gWs = Wq + (n0 + rq) * (size_t)K + sc * 16;

#define STAGE_AB(sb, Tst) do { \
    _Pragma("unroll") \
    for (int j = 0; j < 4; ++j) { \
        gload_lds16(gAs + (size_t)(j * 32) * K + (size_t)(Tst) * 128, \
                    lds + (sb) + j * 4096 + t * 16); \
        gload_lds16(gWs + (size_t)(j * 32) * K + (size_t)(Tst) * 128, \
                    lds + (sb) + 16384 + j * 4096 + t * 16); } } while (0)

    // ---- ds_read lane constants ----
    const int r7 = fr & 7;
    const int coff0 = (fq ^ r7) << 4;
    const int coff1 = coff0 ^ 64;                  // chunk+4 (k 64..127)
    const int aBase = wr * 8192 + fr * 128;
    const int bBase = 16384 + wc * 8192 + fr * 128;

#define LDA(db, m, kb) (*(const int4v*)(lds + (db) + aBase + (m) * 2048 + ((kb) ? coff1 : coff0)))
#define LDB(db, n, kb) (*(const int4v*)(lds + (db) + bBase + (n) * 2048 + ((kb) ? coff1 : coff0)))

    f32x4 accf[4][4];
#pragma unroll
    for (int m = 0; m < 4; ++m)
#pragma unroll
        for (int n = 0; n < 4; ++n)
            accf[m][n] = {0.f, 0.f, 0.f, 0.f};

    const int4v kz = {0, 0, 0, 0};
    const int NT = K >> 7;            // 32 steps (= groups)

    // ---- prologue: stage tile 0 into buf 0; load group-0 scales ----
    STAGE_AB(0, 0);
    float sgc[4], sgn[4];
#pragma unroll
    for (int n = 0; n < 4; ++n)
        sgc[n] = wscale[n0 + wc * 64 + n * 16 + fr];
    asm volatile("s_waitcnt vmcnt(0)" ::: "memory");
    __builtin_amdgcn_s_barrier();

#pragma unroll 1
    for (int T = 0; T < NT; ++T) {
        const int db = (T & 1) << 15;
        const int sb = ((T + 1) & 1) << 15;
        const bool hn = (T + 1) < NT;

        // ---- stage next tile into the other (retired) buffer ----
        if (hn) STAGE_AB(sb, T + 1);
        // ---- prefetch next group's scales ----
        if (hn) {
#pragma unroll
            for (int n = 0; n < 4; ++n)
                sgn[n] = wscale[(size_t)(T + 1) * N + n0 + wc * 64 + n * 16 + fr];
        }

        // ---- resident B fragments (8 reads, 32 VGPR) ----
        int4v b0[4], b1[4];
#pragma unroll
        for (int n = 0; n < 4; ++n) { b0[n] = LDB(db, n, 0); b1[n] = LDB(db, n, 1); }

        // ---- stream A pairs: 2 ds_reads -> 4 chained MFMA pairs + fixups ----
        __builtin_amdgcn_s_setprio(1);
#pragma unroll
        for (int m = 0; m < 4; ++m) {
            const int4v a0 = LDA(db, m, 0);
            const int4v a1 = LDA(db, m, 1);
#pragma unroll
            for (int n = 0; n < 4; ++n) {
                int4v tv = __builtin_amdgcn_mfma_i32_16x16x64_i8(
                    a0, b0[n], kz, 0, 0, 0);
                tv = __builtin_amdgcn_mfma_i32_16x16x64_i8(
                    a1, b1[n], tv, 0, 0, 0);
#pragma unroll
                for (int e = 0; e < 4; ++e)
                    accf[m][n][e] += sgc[n] * (float)tv[e];
            }
        }
        __builtin_amdgcn_s_setprio(0);

        if (hn) {
#pragma unroll
            for (int n = 0; n < 4; ++n) sgc[n] = sgn[n];
        }

        // ---- single step-boundary sync (next tile landed; reads retired) ----
        asm volatile("s_waitcnt vmcnt(0)" ::: "memory");
        __builtin_amdgcn_s_barrier();
    }

    // ---- epilogue 1: scale by per-row sx ----
#pragma unroll
    for (int m = 0; m < 4; ++m) {
        const f32x4 sxv = *(const f32x4*)(sx + m0 + wr * 64 + m * 16 + fq * 4);
#pragma unroll
        for (int n = 0; n < 4; ++n)
#pragma unroll
            for (int e = 0; e < 4; ++e)
                accf[m][n][e] *= sxv[e];
    }

    // ---- epilogue 2: rank-32 zero-point correction via f16 MFMA ----
    {
        f16x8 uf[4], vf[4];
#pragma unroll
        for (int m = 0; m < 4; ++m)
            uf[m] = *(const f16x8*)(U + (m0 + wr * 64 + m * 16 + fr) * 32 + fq * 8);
#pragma unroll
        for (int n = 0; n < 4; ++n)
            vf[n] = *(const f16x8*)(Vneg + (n0 + wc * 64 + n * 16 + fr) * 32 + fq * 8);
#pragma unroll
        for (int m = 0; m < 4; ++m)
#pragma unroll
            for (int n = 0; n < 4; ++n)
                accf[m][n] = __builtin_amdgcn_mfma_f32_16x16x32_f16(
                    uf[m], vf[n], accf[m][n], 0, 0, 0);
    }

    // ---- epilogue 3: + bias, f32 scatter stores (static indices) ----
#pragma unroll
    for (int n = 0; n < 4; ++n) {
        const size_t gcol = n0 + wc * 64 + n * 16 + fr;
        const float bv = bias[gcol];
#pragma unroll
        for (int am = 0; am < 4; ++am) {
            const size_t grow = m0 + wr * 64 + am * 16 + fq * 4;
#pragma unroll
            for (int r = 0; r < 4; ++r)
                C[(grow + r) * N + gcol] = accf[am][n][r] + bv;
        }
    }
}

extern "C" void kernel_launch(void* const* d_in, const int* in_sizes, int n_in,
                              void* d_out, int out_size, void* d_ws, size_t ws_size,
                              hipStream_t stream) {
    const float* x      = (const float*)d_in[0];
    const int* packed   = (const int*)d_in[1];
    const float* wscale = (const float*)d_in[2];
    const float* wzero  = (const float*)d_in[3];
    const float* smooth = (const float*)d_in[4];
    const float* bias   = (const float*)d_in[5];
    float* out = (float*)d_out;

    const int K = in_sizes[4];             // 4096
    const int N = in_sizes[5];             // 11008
    const int M = in_sizes[0] / K;         // 8192
    const size_t MK = (size_t)M * K;
    const size_t NK = (size_t)N * K;

    char* Aq  = (char*)d_ws;
    char* Wq  = Aq + MK;
    f16* U    = (f16*)(Wq + NK);
    f16* Vneg = U + (size_t)M * 32;
    float* sxp = (float*)(Vneg + (size_t)N * 32);

    quantx_kernel<<<(M + 3) / 4, 256, 0, stream>>>(x, smooth, Aq, sxp, U, M, K);
    const int total8 = (int)(NK / 16);
    repackw_kernel<<<(total8 + 255) / 256, 256, 0, stream>>>(packed, Wq, total8);
    vneg_kernel<<<(N * 32 + 255) / 256, 256, 0, stream>>>(wscale, wzero, Vneg, N);

    const int grid_gemm = (M / BM) * (N / BN);
    gemm_kernel<<<grid_gemm, 256, 0, stream>>>(
        Aq, Wq, wscale, sxp, U, Vneg, bias, out, M, N, K);
}